// Round 12
// baseline (804.317 us; speedup 1.0000x reference)
//
#include <hip/hip_runtime.h>
#include <hip/hip_bf16.h>
#include <stdint.h>

// WindowMSA, round 12: barrier-free qkv with fragment-ordered weights.
//  - wcvt emits ALL weights in MFMA-B-fragment order: 8 groups (qs0,qs1,k0,k1,
//    v0,v1,p0,p1), each 96 cols x 192 k = 36 frags x 64 lanes x 16B = 36864 B.
//  - qkv: W frags read straight from global (coalesced, L1/L2-hot, identical
//    addrs across waves/blocks). NO __syncthreads at all: per-wave private
//    LDS transpose strip (16 rows x 208B), same-wave write->read->store.
//    256 thr, M=64, 6 blocks/CU.
//  - attn: identical to round 11 (proj fused, wpf = groups 6,7).

typedef __bf16 bf16;
typedef __attribute__((ext_vector_type(8))) __bf16 bf16x8;
typedef __attribute__((ext_vector_type(4))) float f32x4;

#define CDIM 192
#define NH 6
#define NTOK 49
#define QSCALE 0.17677669529663687f

// ws byte offsets
#define WSB_WF     0u          // frag-ordered weights: 8 groups x 36864 = 294912 B
#define WSB_B5     294912u     // b5L: 64*6*16*256 bf16 = 3,145,728 B
#define WSB_QO     3440640u    // 200704*192 bf16 = 77,070,336 B
#define WSB_K      80510976u
#define WSB_V      157581312u  // end 234,651,648

// qkv LDS: 4 per-wave strips of 16 rows x 208 B = 13312 B total
#define QSTRIP   3328u
#define QSTRIDE  208u
#define QKV_LDS  13312u

// attn LDS: VT region 27904 (voff(191)+128 = 27808), 8 strips of 2304
#define OFF_STRIP 27904u
#define STRIPB    2304u
#define ATTN_LDS  46336u
#define OSTRIDE   400u         // O tile row stride (reuses VT region)

__device__ __forceinline__ uint32_t voff(uint32_t ch) {   // VT row base, 16B-aligned, monotone
  return ch * 144u + ((ch >> 4) << 4);
}
__device__ __forceinline__ uint32_t f2u(float f) { bf16 h = (bf16)f; return (uint32_t)__builtin_bit_cast(uint16_t, h); }
__device__ __forceinline__ bf16x8 lda8(const float* p) {
  float4 w0 = *(const float4*)p;
  float4 w1 = *(const float4*)(p + 4);
  bf16x8 b = {(bf16)w0.x, (bf16)w0.y, (bf16)w0.z, (bf16)w0.w,
              (bf16)w1.x, (bf16)w1.y, (bf16)w1.z, (bf16)w1.w};
  return b;
}
__device__ __forceinline__ float bfu2f(uint32_t lo16) { return __builtin_bit_cast(float, lo16 << 16); }
__device__ __forceinline__ float bfh2f(uint32_t hi16) { return __builtin_bit_cast(float, hi16 & 0xffff0000u); }

// ---- weights f32 -> bf16, fragment-ordered. 18432 threads. ----
// wf[g*2304 + (ntl*6+kk)*64 + lane][8] = W_g[rowb + ntl*16+(lane&15)][kk*32+(lane>>4)*8 .. +8]
__global__ void __launch_bounds__(256)
wcvt_kernel(const float* __restrict__ wqkv, const float* __restrict__ wskip,
            const float* __restrict__ wproj, bf16* __restrict__ wf) {
  uint32_t t = blockIdx.x * 256u + threadIdx.x;           // [0, 18432)
  if (t >= 18432u) return;
  uint32_t g = t / 2304u, rem = t - g * 2304u;
  uint32_t ntlkk = rem >> 6, lane = rem & 63u;
  uint32_t ntl = ntlkk / 6u, kk = ntlkk - ntl * 6u;
  const float* src; uint32_t rowb;
  if (g < 2u)      { src = wskip; rowb = g * 96u; }
  else if (g < 6u) { src = wqkv;  rowb = (g - 2u) * 96u; }
  else             { src = wproj; rowb = (g - 6u) * 96u; }
  uint32_t row = rowb + ntl * 16u + (lane & 15u);
  uint32_t col = kk * 32u + (lane >> 4) * 8u;
  const float* p = src + row * CDIM + col;
  float4 a = *(const float4*)p, b = *(const float4*)(p + 4);
  uint4 o;
  o.x = (f2u(a.y) << 16) | f2u(a.x);
  o.y = (f2u(a.w) << 16) | f2u(a.z);
  o.z = (f2u(b.y) << 16) | f2u(b.x);
  o.w = (f2u(b.w) << 16) | f2u(b.z);
  *(uint4*)(wf + (size_t)t * 8u) = o;
}

// ---- bias for transposed S: t = (((w*6+h)*16 + st*4+nt)*64 + lane)*4 + r
//      i (query) = st*16 + (lane&15) ; j (key) = nt*16 + (lane>>4)*4 + r ----
__global__ void __launch_bounds__(256)
biasprep_kernel(const int* __restrict__ rpi, const float* __restrict__ rpb,
                const float* __restrict__ mask, bf16* __restrict__ b5) {
  uint32_t t = blockIdx.x * 256u + threadIdx.x;
  if (t >= 1572864u) return;
  uint32_t w    = t / 24576u;
  uint32_t rem  = t - w * 24576u;
  uint32_t h    = rem / 4096u;
  uint32_t rem2 = rem & 4095u;
  uint32_t stnt = rem2 >> 8, lane = (rem2 >> 2) & 63u, r = rem2 & 3u;
  uint32_t i = (stnt >> 2) * 16u + (lane & 15u);
  uint32_t j = (stnt & 3u) * 16u + (lane >> 4) * 4u + r;
  float v;
  if (j >= NTOK)      v = -1e30f;
  else if (i >= NTOK) v = 0.f;
  else v = rpb[(uint32_t)rpi[i * NTOK + j] * NH + h] + mask[(size_t)w * (NTOK * NTOK) + i * NTOK + j];
  b5[t] = (bf16)v;
}

// ---- fused QKV GEMM: barrier-free, 6 frag-W phases, M=64/block, 256 thr ----
__global__ void __launch_bounds__(256, 6)
qkv_kernel(const float* __restrict__ skip, const float* __restrict__ x,
           const bf16* __restrict__ wf, const float* __restrict__ bskip,
           const float* __restrict__ bqkv, bf16* __restrict__ qo,
           bf16* __restrict__ kbf, bf16* __restrict__ vbf) {
  extern __shared__ char lds[];
  const uint32_t tid = threadIdx.x, lane = tid & 63u, wv = tid >> 6;  // 4 waves
  const uint32_t l15 = lane & 15u, lg = lane >> 4;
  const uint32_t rowbase = blockIdx.x * 64u;
  const uint32_t arow = rowbase + wv * 16u + l15;
  char* strip = lds + wv * QSTRIP;

  bf16x8 af[6];
  #pragma unroll
  for (uint32_t p = 0; p < 6u; ++p) {
    if (p == 0u || p == 2u) {
      const float* ap = (p ? x : skip) + (size_t)arow * CDIM + lg * 8u;
      #pragma unroll
      for (uint32_t kk = 0; kk < 6u; ++kk) af[kk] = lda8(ap + kk * 32u);
    }
    const bf16* wg = wf + p * 18432u;
    f32x4 acc[6] = {};
    #pragma unroll
    for (uint32_t kk = 0; kk < 6u; ++kk)
      #pragma unroll
      for (uint32_t ntl = 0; ntl < 6u; ++ntl) {
        bf16x8 wb = *(const bf16x8*)(wg + (((ntl * 6u + kk) << 6) + lane) * 8u);
        acc[ntl] = __builtin_amdgcn_mfma_f32_16x16x32_bf16(af[kk], wb, acc[ntl], 0, 0, 0);
      }
    const float* bias_base = (p < 2u) ? bskip + (p & 1u) * 96u : bqkv + (p - 2u) * 96u;
    const float scale = (p < 2u) ? QSCALE : 1.0f;
    // D-layout -> own strip (same wave; DS ops are in-order, no barrier)
    #pragma unroll
    for (uint32_t ntl = 0; ntl < 6u; ++ntl) {
      float bias = bias_base[ntl * 16u + l15];
      #pragma unroll
      for (uint32_t r = 0; r < 4u; ++r)
        *(bf16*)(strip + (lg * 4u + r) * QSTRIDE + (ntl * 16u + l15) * 2u) =
            (bf16)((acc[ntl][r] + bias) * scale);
    }
    // copy out own 16 rows x 96 cols: 192 uint4, 3 per lane
    bf16* dst = (p < 2u) ? qo : ((p < 4u) ? kbf : vbf);
    const uint32_t colofs = (p & 1u) * 96u;
    #pragma unroll
    for (uint32_t it = 0; it < 3u; ++it) {
      uint32_t u = it * 64u + lane;
      uint32_t row = u / 12u, c16 = u - row * 12u;
      uint4 v = *(const uint4*)(strip + row * QSTRIDE + c16 * 16u);
      *(uint4*)(dst + (size_t)(rowbase + wv * 16u + row) * CDIM + colofs + c16 * 8u) = v;
    }
  }
}

// ---- attention + proj: one block per window, 512 thr ----
__global__ void __launch_bounds__(512, 6)
attn_kernel(const bf16* __restrict__ qo, const bf16* __restrict__ kbf,
            const bf16* __restrict__ vbf, const bf16* __restrict__ b5L,
            const bf16* __restrict__ wpf, const float* __restrict__ bproj,
            float* __restrict__ out) {
  extern __shared__ char lds[];
  const uint32_t tid = threadIdx.x, lane = tid & 63u, wv = tid >> 6;
  const uint32_t l15 = lane & 15u, lg = lane >> 4;
  const uint32_t grp = wv >> 2, st = wv & 3u;
  const uint32_t win = blockIdx.x;
  char* strip = lds + OFF_STRIP + wv * STRIPB;
  const size_t wrow0 = (size_t)win * NTOK;

  // ---- stage V transposed, tok-pair packed b32 writes ----
  for (uint32_t i = tid; i < 600u; i += 512u) {          // 25 pairs x 24 c16
    uint32_t pair = i / 24u, c16 = i - pair * 24u;
    uint32_t tok0 = pair * 2u;
    const bf16* src = vbf + (wrow0 + tok0) * CDIM + c16 * 8u;
    uint4 a = *(const uint4*)src;
    uint4 b = make_uint4(0u, 0u, 0u, 0u);
    if (tok0 + 1u < NTOK) b = *(const uint4*)(src + CDIM);
    uint32_t base = voff(c16 * 8u) + tok0 * 2u;
    uint32_t aw[4] = {a.x, a.y, a.z, a.w};
    uint32_t bw[4] = {b.x, b.y, b.z, b.w};
    #pragma unroll
    for (uint32_t q = 0; q < 4u; ++q) {
      *(uint32_t*)(lds + base + (2u * q) * 144u)      = (aw[q] & 0xffffu) | (bw[q] << 16);
      *(uint32_t*)(lds + base + (2u * q + 1u) * 144u) = (aw[q] >> 16) | (bw[q] & 0xffff0000u);
    }
  }
  for (uint32_t i = tid; i < 1344u; i += 512u) {         // zero toks 50..63
    uint32_t ch = i / 7u, p = i - ch * 7u;
    *(uint32_t*)(lds + voff(ch) + (50u + p * 2u) * 2u) = 0u;
  }
  __syncthreads();

  f32x4 oacc[3][2];
  uint32_t qrow = st * 16u + l15; if (qrow > 48u) qrow = 48u;
  const uint32_t w6 = win & 63u;

  #pragma unroll
  for (uint32_t hl = 0; hl < 3u; ++hl) {
    uint32_t h = grp * 3u + hl;
    bf16x8 qb = *(const bf16x8*)(qo + (wrow0 + qrow) * CDIM + h * 32u + lg * 8u);
    f32x4 s[4];
    #pragma unroll
    for (uint32_t nt = 0; nt < 4u; ++nt) {
      uint32_t krow = nt * 16u + l15; if (krow > 48u) krow = 48u;
      bf16x8 ka = *(const bf16x8*)(kbf + (wrow0 + krow) * CDIM + h * 32u + lg * 8u);
      f32x4 z = {};
      s[nt] = __builtin_amdgcn_mfma_f32_16x16x32_bf16(ka, qb, z, 0, 0, 0);
    }
    const bf16* bp = b5L + ((((w6 * 6u + h) * 16u) + st * 4u) << 8) + lane * 4u;
    #pragma unroll
    for (uint32_t nt = 0; nt < 4u; ++nt) {
      uint2 bv = *(const uint2*)(bp + nt * 256u);
      s[nt][0] += bfu2f(bv.x);
      s[nt][1] += bfh2f(bv.x);
      s[nt][2] += bfu2f(bv.y);
      s[nt][3] += bfh2f(bv.y);
    }
    float mm = s[0][0];
    #pragma unroll
    for (uint32_t nt = 0; nt < 4u; ++nt)
      #pragma unroll
      for (uint32_t r = 0; r < 4u; ++r) mm = fmaxf(mm, s[nt][r]);
    mm = fmaxf(mm, __shfl_xor(mm, 16)); mm = fmaxf(mm, __shfl_xor(mm, 32));
    float ss = 0.f;
    #pragma unroll
    for (uint32_t nt = 0; nt < 4u; ++nt)
      #pragma unroll
      for (uint32_t r = 0; r < 4u; ++r) { float p = __expf(s[nt][r] - mm); s[nt][r] = p; ss += p; }
    ss += __shfl_xor(ss, 16); ss += __shfl_xor(ss, 32);
    float inv = 1.f / ss;
    #pragma unroll
    for (uint32_t nt = 0; nt < 4u; ++nt) {
      uint2 w;
      w.x = (f2u(s[nt][1] * inv) << 16) | f2u(s[nt][0] * inv);
      w.y = (f2u(s[nt][3] * inv) << 16) | f2u(s[nt][2] * inv);
      *(uint2*)(strip + l15 * 144u + nt * 32u + lg * 8u) = w;
    }
    bf16x8 pb0 = *(const bf16x8*)(strip + l15 * 144u + lg * 16u);
    bf16x8 pb1 = *(const bf16x8*)(strip + l15 * 144u + 64u + lg * 16u);
    #pragma unroll
    for (uint32_t nt2 = 0; nt2 < 2u; ++nt2) {
      uint32_t ch = h * 32u + nt2 * 16u + l15;
      uint32_t va = voff(ch);
      bf16x8 va0 = *(const bf16x8*)(lds + va + lg * 16u);
      bf16x8 va1 = *(const bf16x8*)(lds + va + 64u + lg * 16u);
      f32x4 z = {};
      f32x4 o = __builtin_amdgcn_mfma_f32_16x16x32_bf16(va0, pb0, z, 0, 0, 0);
      oacc[hl][nt2] = __builtin_amdgcn_mfma_f32_16x16x32_bf16(va1, pb1, o, 0, 0, 0);
    }
  }

  __syncthreads();   // all VT/strip reads done -> reuse VT region as O tile

  {
    uint32_t orow = (st * 16u + l15) * OSTRIDE;
    #pragma unroll
    for (uint32_t hl = 0; hl < 3u; ++hl)
      #pragma unroll
      for (uint32_t nt2 = 0; nt2 < 2u; ++nt2) {
        uint32_t d0 = (grp * 3u + hl) * 32u + nt2 * 16u + lg * 4u;
        uint2 w;
        w.x = (f2u(oacc[hl][nt2][1]) << 16) | f2u(oacc[hl][nt2][0]);
        w.y = (f2u(oacc[hl][nt2][3]) << 16) | f2u(oacc[hl][nt2][2]);
        *(uint2*)(lds + orow + d0 * 2u) = w;
      }
  }

  __syncthreads();   // O tile ready -> fused proj (fragment-ordered W, coalesced)

  {
    const uint32_t st2 = (wv & 3u) * 16u;        // row strip
    const uint32_t ntlg0 = (wv >> 2) * 6u;       // output-channel half
    bf16x8 paf[6];
    #pragma unroll
    for (uint32_t kk = 0; kk < 6u; ++kk)
      paf[kk] = *(const bf16x8*)(lds + (st2 + l15) * OSTRIDE + kk * 64u + lg * 16u);
    f32x4 pacc[6] = {};
    #pragma unroll
    for (uint32_t kk = 0; kk < 6u; ++kk)
      #pragma unroll
      for (uint32_t ntl = 0; ntl < 6u; ++ntl) {
        bf16x8 wb = *(const bf16x8*)(wpf + (((ntlg0 + ntl) * 6u + kk) * 64u + lane) * 8u);
        pacc[ntl] = __builtin_amdgcn_mfma_f32_16x16x32_bf16(paf[kk], wb, pacc[ntl], 0, 0, 0);
      }
    #pragma unroll
    for (uint32_t ntl = 0; ntl < 6u; ++ntl) {
      uint32_t ch = (ntlg0 + ntl) * 16u + l15;
      float bias = bproj[ch];
      #pragma unroll
      for (uint32_t r = 0; r < 4u; ++r) {
        uint32_t row = st2 + lg * 4u + r;
        if (row < NTOK)
          out[(wrow0 + row) * CDIM + ch] = pacc[ntl][r] + bias;
      }
    }
  }
}

extern "C" void kernel_launch(void* const* d_in, const int* in_sizes, int n_in,
                              void* d_out, int out_size, void* d_ws, size_t ws_size,
                              hipStream_t stream) {
  const float* x     = (const float*)d_in[0];
  const float* skip  = (const float*)d_in[1];
  const float* mask  = (const float*)d_in[2];
  const int*   rpi   = (const int*)  d_in[3];
  const float* rpb   = (const float*)d_in[4];
  const float* wqkv  = (const float*)d_in[5];
  const float* bqkv  = (const float*)d_in[6];
  const float* wskip = (const float*)d_in[7];
  const float* bskip = (const float*)d_in[8];
  const float* wproj = (const float*)d_in[9];
  const float* bproj = (const float*)d_in[10];

  char* ws = (char*)d_ws;
  bf16* wf   = (bf16*)(ws + WSB_WF);
  bf16* b5L  = (bf16*)(ws + WSB_B5);
  bf16* qo   = (bf16*)(ws + WSB_QO);
  bf16* kbf  = (bf16*)(ws + WSB_K);
  bf16* vbf  = (bf16*)(ws + WSB_V);

  uint32_t nwin  = (uint32_t)(in_sizes[0] / (NTOK * CDIM));
  uint32_t nrows = nwin * NTOK;            // 200704, divisible by 64
  uint32_t ngb   = nrows / 64u;

  hipFuncSetAttribute((const void*)attn_kernel, hipFuncAttributeMaxDynamicSharedMemorySize, (int)ATTN_LDS);

  wcvt_kernel<<<72, 256, 0, stream>>>(wqkv, wskip, wproj, wf);
  biasprep_kernel<<<6144, 256, 0, stream>>>(rpi, rpb, mask, b5L);
  qkv_kernel<<<ngb, 256, QKV_LDS, stream>>>(skip, x, wf, bskip, bqkv, qo, kbf, vbf);
  attn_kernel<<<nwin, 512, ATTN_LDS, stream>>>(qo, kbf, vbf, b5L,
                                               wf + 110592u, bproj, (float*)d_out);
}

// Round 13
// 427.334 us; speedup vs baseline: 1.8822x; 1.8822x over previous
//
#include <hip/hip_runtime.h>
#include <hip/hip_bf16.h>
#include <stdint.h>

// WindowMSA, round 13: round-12 design, launch-bounds fix.
//  - r12 post-mortem: __launch_bounds__(256,6) capped VGPR at ~85 (split
//    arch/acc) -> acc/af spilled to scratch every phase: WRITE_SIZE 1.22GB,
//    dur 665us. Fix: (256,4) -> cap 128, spill-free (r10/r11 ran VGPR=56).
//  - qkv: barrier-free, fragment-ordered W read straight from global
//    (coalesced, L2-hot), per-wave private LDS transpose strip, M=64.
//  - attn: proj fused with fragment-ordered wproj (unchanged from r11/r12).

typedef __bf16 bf16;
typedef __attribute__((ext_vector_type(8))) __bf16 bf16x8;
typedef __attribute__((ext_vector_type(4))) float f32x4;

#define CDIM 192
#define NH 6
#define NTOK 49
#define QSCALE 0.17677669529663687f

// ws byte offsets
#define WSB_WF     0u          // frag-ordered weights: 8 groups x 36864 = 294912 B
#define WSB_B5     294912u     // b5L: 64*6*16*256 bf16 = 3,145,728 B
#define WSB_QO     3440640u    // 200704*192 bf16 = 77,070,336 B
#define WSB_K      80510976u
#define WSB_V      157581312u  // end 234,651,648

// qkv LDS: 4 per-wave strips of 16 rows x 208 B = 13312 B total
#define QSTRIP   3328u
#define QSTRIDE  208u
#define QKV_LDS  13312u

// attn LDS: VT region 27904 (voff(191)+128 = 27808), 8 strips of 2304
#define OFF_STRIP 27904u
#define STRIPB    2304u
#define ATTN_LDS  46336u
#define OSTRIDE   400u         // O tile row stride (reuses VT region)

__device__ __forceinline__ uint32_t voff(uint32_t ch) {   // VT row base, 16B-aligned, monotone
  return ch * 144u + ((ch >> 4) << 4);
}
__device__ __forceinline__ uint32_t f2u(float f) { bf16 h = (bf16)f; return (uint32_t)__builtin_bit_cast(uint16_t, h); }
__device__ __forceinline__ bf16x8 lda8(const float* p) {
  float4 w0 = *(const float4*)p;
  float4 w1 = *(const float4*)(p + 4);
  bf16x8 b = {(bf16)w0.x, (bf16)w0.y, (bf16)w0.z, (bf16)w0.w,
              (bf16)w1.x, (bf16)w1.y, (bf16)w1.z, (bf16)w1.w};
  return b;
}
__device__ __forceinline__ float bfu2f(uint32_t lo16) { return __builtin_bit_cast(float, lo16 << 16); }
__device__ __forceinline__ float bfh2f(uint32_t hi16) { return __builtin_bit_cast(float, hi16 & 0xffff0000u); }

// ---- weights f32 -> bf16, fragment-ordered. 18432 threads. ----
// wf[g*2304 + (ntl*6+kk)*64 + lane][8] = W_g[rowb + ntl*16+(lane&15)][kk*32+(lane>>4)*8 .. +8]
__global__ void __launch_bounds__(256)
wcvt_kernel(const float* __restrict__ wqkv, const float* __restrict__ wskip,
            const float* __restrict__ wproj, bf16* __restrict__ wf) {
  uint32_t t = blockIdx.x * 256u + threadIdx.x;           // [0, 18432)
  if (t >= 18432u) return;
  uint32_t g = t / 2304u, rem = t - g * 2304u;
  uint32_t ntlkk = rem >> 6, lane = rem & 63u;
  uint32_t ntl = ntlkk / 6u, kk = ntlkk - ntl * 6u;
  const float* src; uint32_t rowb;
  if (g < 2u)      { src = wskip; rowb = g * 96u; }
  else if (g < 6u) { src = wqkv;  rowb = (g - 2u) * 96u; }
  else             { src = wproj; rowb = (g - 6u) * 96u; }
  uint32_t row = rowb + ntl * 16u + (lane & 15u);
  uint32_t col = kk * 32u + (lane >> 4) * 8u;
  const float* p = src + row * CDIM + col;
  float4 a = *(const float4*)p, b = *(const float4*)(p + 4);
  uint4 o;
  o.x = (f2u(a.y) << 16) | f2u(a.x);
  o.y = (f2u(a.w) << 16) | f2u(a.z);
  o.z = (f2u(b.y) << 16) | f2u(b.x);
  o.w = (f2u(b.w) << 16) | f2u(b.z);
  *(uint4*)(wf + (size_t)t * 8u) = o;
}

// ---- bias for transposed S: t = (((w*6+h)*16 + st*4+nt)*64 + lane)*4 + r
//      i (query) = st*16 + (lane&15) ; j (key) = nt*16 + (lane>>4)*4 + r ----
__global__ void __launch_bounds__(256)
biasprep_kernel(const int* __restrict__ rpi, const float* __restrict__ rpb,
                const float* __restrict__ mask, bf16* __restrict__ b5) {
  uint32_t t = blockIdx.x * 256u + threadIdx.x;
  if (t >= 1572864u) return;
  uint32_t w    = t / 24576u;
  uint32_t rem  = t - w * 24576u;
  uint32_t h    = rem / 4096u;
  uint32_t rem2 = rem & 4095u;
  uint32_t stnt = rem2 >> 8, lane = (rem2 >> 2) & 63u, r = rem2 & 3u;
  uint32_t i = (stnt >> 2) * 16u + (lane & 15u);
  uint32_t j = (stnt & 3u) * 16u + (lane >> 4) * 4u + r;
  float v;
  if (j >= NTOK)      v = -1e30f;
  else if (i >= NTOK) v = 0.f;
  else v = rpb[(uint32_t)rpi[i * NTOK + j] * NH + h] + mask[(size_t)w * (NTOK * NTOK) + i * NTOK + j];
  b5[t] = (bf16)v;
}

// ---- fused QKV GEMM: barrier-free, 6 frag-W phases, M=64/block, 256 thr ----
__global__ void __launch_bounds__(256, 4)
qkv_kernel(const float* __restrict__ skip, const float* __restrict__ x,
           const bf16* __restrict__ wf, const float* __restrict__ bskip,
           const float* __restrict__ bqkv, bf16* __restrict__ qo,
           bf16* __restrict__ kbf, bf16* __restrict__ vbf) {
  extern __shared__ char lds[];
  const uint32_t tid = threadIdx.x, lane = tid & 63u, wv = tid >> 6;  // 4 waves
  const uint32_t l15 = lane & 15u, lg = lane >> 4;
  const uint32_t rowbase = blockIdx.x * 64u;
  const uint32_t arow = rowbase + wv * 16u + l15;
  char* strip = lds + wv * QSTRIP;

  bf16x8 af[6];
  #pragma unroll
  for (uint32_t p = 0; p < 6u; ++p) {
    if (p == 0u || p == 2u) {
      const float* ap = (p ? x : skip) + (size_t)arow * CDIM + lg * 8u;
      #pragma unroll
      for (uint32_t kk = 0; kk < 6u; ++kk) af[kk] = lda8(ap + kk * 32u);
    }
    const bf16* wg = wf + p * 18432u;
    f32x4 acc[6] = {};
    #pragma unroll
    for (uint32_t kk = 0; kk < 6u; ++kk)
      #pragma unroll
      for (uint32_t ntl = 0; ntl < 6u; ++ntl) {
        bf16x8 wb = *(const bf16x8*)(wg + (((ntl * 6u + kk) << 6) + lane) * 8u);
        acc[ntl] = __builtin_amdgcn_mfma_f32_16x16x32_bf16(af[kk], wb, acc[ntl], 0, 0, 0);
      }
    const float* bias_base = (p < 2u) ? bskip + (p & 1u) * 96u : bqkv + (p - 2u) * 96u;
    const float scale = (p < 2u) ? QSCALE : 1.0f;
    // D-layout -> own strip (same wave; DS ops are in-order, no barrier)
    #pragma unroll
    for (uint32_t ntl = 0; ntl < 6u; ++ntl) {
      float bias = bias_base[ntl * 16u + l15];
      #pragma unroll
      for (uint32_t r = 0; r < 4u; ++r)
        *(bf16*)(strip + (lg * 4u + r) * QSTRIDE + (ntl * 16u + l15) * 2u) =
            (bf16)((acc[ntl][r] + bias) * scale);
    }
    // copy out own 16 rows x 96 cols: 192 uint4, 3 per lane
    bf16* dst = (p < 2u) ? qo : ((p < 4u) ? kbf : vbf);
    const uint32_t colofs = (p & 1u) * 96u;
    #pragma unroll
    for (uint32_t it = 0; it < 3u; ++it) {
      uint32_t u = it * 64u + lane;
      uint32_t row = u / 12u, c16 = u - row * 12u;
      uint4 v = *(const uint4*)(strip + row * QSTRIDE + c16 * 16u);
      *(uint4*)(dst + (size_t)(rowbase + wv * 16u + row) * CDIM + colofs + c16 * 8u) = v;
    }
  }
}

// ---- attention + proj: one block per window, 512 thr ----
__global__ void __launch_bounds__(512, 6)
attn_kernel(const bf16* __restrict__ qo, const bf16* __restrict__ kbf,
            const bf16* __restrict__ vbf, const bf16* __restrict__ b5L,
            const bf16* __restrict__ wpf, const float* __restrict__ bproj,
            float* __restrict__ out) {
  extern __shared__ char lds[];
  const uint32_t tid = threadIdx.x, lane = tid & 63u, wv = tid >> 6;
  const uint32_t l15 = lane & 15u, lg = lane >> 4;
  const uint32_t grp = wv >> 2, st = wv & 3u;
  const uint32_t win = blockIdx.x;
  char* strip = lds + OFF_STRIP + wv * STRIPB;
  const size_t wrow0 = (size_t)win * NTOK;

  // ---- stage V transposed, tok-pair packed b32 writes ----
  for (uint32_t i = tid; i < 600u; i += 512u) {          // 25 pairs x 24 c16
    uint32_t pair = i / 24u, c16 = i - pair * 24u;
    uint32_t tok0 = pair * 2u;
    const bf16* src = vbf + (wrow0 + tok0) * CDIM + c16 * 8u;
    uint4 a = *(const uint4*)src;
    uint4 b = make_uint4(0u, 0u, 0u, 0u);
    if (tok0 + 1u < NTOK) b = *(const uint4*)(src + CDIM);
    uint32_t base = voff(c16 * 8u) + tok0 * 2u;
    uint32_t aw[4] = {a.x, a.y, a.z, a.w};
    uint32_t bw[4] = {b.x, b.y, b.z, b.w};
    #pragma unroll
    for (uint32_t q = 0; q < 4u; ++q) {
      *(uint32_t*)(lds + base + (2u * q) * 144u)      = (aw[q] & 0xffffu) | (bw[q] << 16);
      *(uint32_t*)(lds + base + (2u * q + 1u) * 144u) = (aw[q] >> 16) | (bw[q] & 0xffff0000u);
    }
  }
  for (uint32_t i = tid; i < 1344u; i += 512u) {         // zero toks 50..63
    uint32_t ch = i / 7u, p = i - ch * 7u;
    *(uint32_t*)(lds + voff(ch) + (50u + p * 2u) * 2u) = 0u;
  }
  __syncthreads();

  f32x4 oacc[3][2];
  uint32_t qrow = st * 16u + l15; if (qrow > 48u) qrow = 48u;
  const uint32_t w6 = win & 63u;

  #pragma unroll
  for (uint32_t hl = 0; hl < 3u; ++hl) {
    uint32_t h = grp * 3u + hl;
    bf16x8 qb = *(const bf16x8*)(qo + (wrow0 + qrow) * CDIM + h * 32u + lg * 8u);
    f32x4 s[4];
    #pragma unroll
    for (uint32_t nt = 0; nt < 4u; ++nt) {
      uint32_t krow = nt * 16u + l15; if (krow > 48u) krow = 48u;
      bf16x8 ka = *(const bf16x8*)(kbf + (wrow0 + krow) * CDIM + h * 32u + lg * 8u);
      f32x4 z = {};
      s[nt] = __builtin_amdgcn_mfma_f32_16x16x32_bf16(ka, qb, z, 0, 0, 0);
    }
    const bf16* bp = b5L + ((((w6 * 6u + h) * 16u) + st * 4u) << 8) + lane * 4u;
    #pragma unroll
    for (uint32_t nt = 0; nt < 4u; ++nt) {
      uint2 bv = *(const uint2*)(bp + nt * 256u);
      s[nt][0] += bfu2f(bv.x);
      s[nt][1] += bfh2f(bv.x);
      s[nt][2] += bfu2f(bv.y);
      s[nt][3] += bfh2f(bv.y);
    }
    float mm = s[0][0];
    #pragma unroll
    for (uint32_t nt = 0; nt < 4u; ++nt)
      #pragma unroll
      for (uint32_t r = 0; r < 4u; ++r) mm = fmaxf(mm, s[nt][r]);
    mm = fmaxf(mm, __shfl_xor(mm, 16)); mm = fmaxf(mm, __shfl_xor(mm, 32));
    float ss = 0.f;
    #pragma unroll
    for (uint32_t nt = 0; nt < 4u; ++nt)
      #pragma unroll
      for (uint32_t r = 0; r < 4u; ++r) { float p = __expf(s[nt][r] - mm); s[nt][r] = p; ss += p; }
    ss += __shfl_xor(ss, 16); ss += __shfl_xor(ss, 32);
    float inv = 1.f / ss;
    #pragma unroll
    for (uint32_t nt = 0; nt < 4u; ++nt) {
      uint2 w;
      w.x = (f2u(s[nt][1] * inv) << 16) | f2u(s[nt][0] * inv);
      w.y = (f2u(s[nt][3] * inv) << 16) | f2u(s[nt][2] * inv);
      *(uint2*)(strip + l15 * 144u + nt * 32u + lg * 8u) = w;
    }
    bf16x8 pb0 = *(const bf16x8*)(strip + l15 * 144u + lg * 16u);
    bf16x8 pb1 = *(const bf16x8*)(strip + l15 * 144u + 64u + lg * 16u);
    #pragma unroll
    for (uint32_t nt2 = 0; nt2 < 2u; ++nt2) {
      uint32_t ch = h * 32u + nt2 * 16u + l15;
      uint32_t va = voff(ch);
      bf16x8 va0 = *(const bf16x8*)(lds + va + lg * 16u);
      bf16x8 va1 = *(const bf16x8*)(lds + va + 64u + lg * 16u);
      f32x4 z = {};
      f32x4 o = __builtin_amdgcn_mfma_f32_16x16x32_bf16(va0, pb0, z, 0, 0, 0);
      oacc[hl][nt2] = __builtin_amdgcn_mfma_f32_16x16x32_bf16(va1, pb1, o, 0, 0, 0);
    }
  }

  __syncthreads();   // all VT/strip reads done -> reuse VT region as O tile

  {
    uint32_t orow = (st * 16u + l15) * OSTRIDE;
    #pragma unroll
    for (uint32_t hl = 0; hl < 3u; ++hl)
      #pragma unroll
      for (uint32_t nt2 = 0; nt2 < 2u; ++nt2) {
        uint32_t d0 = (grp * 3u + hl) * 32u + nt2 * 16u + lg * 4u;
        uint2 w;
        w.x = (f2u(oacc[hl][nt2][1]) << 16) | f2u(oacc[hl][nt2][0]);
        w.y = (f2u(oacc[hl][nt2][3]) << 16) | f2u(oacc[hl][nt2][2]);
        *(uint2*)(lds + orow + d0 * 2u) = w;
      }
  }

  __syncthreads();   // O tile ready -> fused proj (fragment-ordered W, coalesced)

  {
    const uint32_t st2 = (wv & 3u) * 16u;        // row strip
    const uint32_t ntlg0 = (wv >> 2) * 6u;       // output-channel half
    bf16x8 paf[6];
    #pragma unroll
    for (uint32_t kk = 0; kk < 6u; ++kk)
      paf[kk] = *(const bf16x8*)(lds + (st2 + l15) * OSTRIDE + kk * 64u + lg * 16u);
    f32x4 pacc[6] = {};
    #pragma unroll
    for (uint32_t kk = 0; kk < 6u; ++kk)
      #pragma unroll
      for (uint32_t ntl = 0; ntl < 6u; ++ntl) {
        bf16x8 wb = *(const bf16x8*)(wpf + (((ntlg0 + ntl) * 6u + kk) * 64u + lane) * 8u);
        pacc[ntl] = __builtin_amdgcn_mfma_f32_16x16x32_bf16(paf[kk], wb, pacc[ntl], 0, 0, 0);
      }
    #pragma unroll
    for (uint32_t ntl = 0; ntl < 6u; ++ntl) {
      uint32_t ch = (ntlg0 + ntl) * 16u + l15;
      float bias = bproj[ch];
      #pragma unroll
      for (uint32_t r = 0; r < 4u; ++r) {
        uint32_t row = st2 + lg * 4u + r;
        if (row < NTOK)
          out[(wrow0 + row) * CDIM + ch] = pacc[ntl][r] + bias;
      }
    }
  }
}

extern "C" void kernel_launch(void* const* d_in, const int* in_sizes, int n_in,
                              void* d_out, int out_size, void* d_ws, size_t ws_size,
                              hipStream_t stream) {
  const float* x     = (const float*)d_in[0];
  const float* skip  = (const float*)d_in[1];
  const float* mask  = (const float*)d_in[2];
  const int*   rpi   = (const int*)  d_in[3];
  const float* rpb   = (const float*)d_in[4];
  const float* wqkv  = (const float*)d_in[5];
  const float* bqkv  = (const float*)d_in[6];
  const float* wskip = (const float*)d_in[7];
  const float* bskip = (const float*)d_in[8];
  const float* wproj = (const float*)d_in[9];
  const float* bproj = (const float*)d_in[10];

  char* ws = (char*)d_ws;
  bf16* wf   = (bf16*)(ws + WSB_WF);
  bf16* b5L  = (bf16*)(ws + WSB_B5);
  bf16* qo   = (bf16*)(ws + WSB_QO);
  bf16* kbf  = (bf16*)(ws + WSB_K);
  bf16* vbf  = (bf16*)(ws + WSB_V);

  uint32_t nwin  = (uint32_t)(in_sizes[0] / (NTOK * CDIM));
  uint32_t nrows = nwin * NTOK;            // 200704, divisible by 64
  uint32_t ngb   = nrows / 64u;

  hipFuncSetAttribute((const void*)attn_kernel, hipFuncAttributeMaxDynamicSharedMemorySize, (int)ATTN_LDS);

  wcvt_kernel<<<72, 256, 0, stream>>>(wqkv, wskip, wproj, wf);
  biasprep_kernel<<<6144, 256, 0, stream>>>(rpi, rpb, mask, b5L);
  qkv_kernel<<<ngb, 256, QKV_LDS, stream>>>(skip, x, wf, bskip, bqkv, qo, kbf, vbf);
  attn_kernel<<<nwin, 512, ATTN_LDS, stream>>>(qo, kbf, vbf, b5L,
                                               wf + 110592u, bproj, (float*)d_out);
}

// Round 14
// 329.099 us; speedup vs baseline: 2.4440x; 1.2985x over previous
//
#include <hip/hip_runtime.h>
#include <hip/hip_bf16.h>
#include <stdint.h>

// WindowMSA, round 14: best-of assembly.
//  - qkv: EXACT round-10 structure (measured 153us): 256 thr, M=64, six
//    half-W phases LDS-staged (36KB, 4 blocks/CU), LDS-transposed stores.
//    (r13's barrier-free variant was latency-bound at 290us: per-MFMA
//    dependent global W loads, ~3 in flight at VGPR=64.)
//  - attn: EXACT round-13 kernel (~125us): double-swapped MFMA softmax-in-reg,
//    V transposed in LDS (voff), bias pre-baked in D-layout, proj fused with
//    fragment-ordered wproj (coalesced B-frag loads).

typedef __bf16 bf16;
typedef __attribute__((ext_vector_type(8))) __bf16 bf16x8;
typedef __attribute__((ext_vector_type(4))) float f32x4;

#define CDIM 192
#define NH 6
#define NTOK 49
#define QSCALE 0.17677669529663687f

// ws byte offsets
#define WSB_W      0u          // linear bf16 weights: wqkv|wskip|wproj = 294912 B
#define WSE_WSKIP  73728u      // elem offsets within linear blob
#define WSB_WPF    294912u     // wproj fragment-ordered: 36864 bf16 = 73728 B
#define WSB_B5     368640u     // b5L: 64*6*16*256 bf16 = 3,145,728 B
#define WSB_QO     3514368u    // 200704*192 bf16 = 77,070,336 B
#define WSB_K      80584704u
#define WSB_V      157655040u  // end 234,725,376

// qkv LDS: 96-row W stage (36864 B); transpose tile reuses first 13312 B
#define QKV_LDS  36864u
#define QTSTRIDE 208u

// attn LDS: VT region 27904 (voff(191)+128 = 27808), 8 strips of 2304
#define OFF_STRIP 27904u
#define STRIPB    2304u
#define ATTN_LDS  46336u
#define OSTRIDE   400u         // O tile row stride (reuses VT region)

__device__ __forceinline__ uint32_t swz384(uint32_t row, uint32_t b) {
  return row * 384u + (b ^ ((row & 7u) << 4));
}
__device__ __forceinline__ uint32_t voff(uint32_t ch) {   // VT row base, 16B-aligned, monotone
  return ch * 144u + ((ch >> 4) << 4);
}
__device__ __forceinline__ uint32_t f2u(float f) { bf16 h = (bf16)f; return (uint32_t)__builtin_bit_cast(uint16_t, h); }
__device__ __forceinline__ bf16x8 lda8(const float* p) {
  float4 w0 = *(const float4*)p;
  float4 w1 = *(const float4*)(p + 4);
  bf16x8 b = {(bf16)w0.x, (bf16)w0.y, (bf16)w0.z, (bf16)w0.w,
              (bf16)w1.x, (bf16)w1.y, (bf16)w1.z, (bf16)w1.w};
  return b;
}
__device__ __forceinline__ float bfu2f(uint32_t lo16) { return __builtin_bit_cast(float, lo16 << 16); }
__device__ __forceinline__ float bfh2f(uint32_t hi16) { return __builtin_bit_cast(float, hi16 & 0xffff0000u); }

// ---- weights f32 -> bf16 (linear) + wproj fragment-ordered copy ----
__global__ void __launch_bounds__(256)
wcvt_kernel(const float* __restrict__ wqkv, const float* __restrict__ wskip,
            const float* __restrict__ wproj, bf16* __restrict__ ws,
            bf16* __restrict__ wpf) {
  uint32_t i4 = blockIdx.x * 256u + threadIdx.x;
  uint32_t i = i4 * 4u;
  if (i < 147456u) {
    float4 v;
    if (i < 73728u)       v = *(const float4*)(wqkv + i);
    else if (i < 110592u) v = *(const float4*)(wskip + (i - 73728u));
    else                  v = *(const float4*)(wproj + (i - 110592u));
    *(uint2*)(ws + i) = make_uint2((f2u(v.y) << 16) | f2u(v.x), (f2u(v.w) << 16) | f2u(v.z));
  } else if (i < 184320u) {
    // wpf[((ntl*6+kk)*64+lane)*8+j] = wproj[ntl*16+(lane&15)][kk*32+(lane>>4)*8+j]
    uint32_t f4 = i4 - 36864u;              // [0, 9216)
    uint32_t j0 = (f4 & 1u) * 4u;
    uint32_t lane = (f4 >> 1) & 63u;
    uint32_t kkntl = f4 >> 7;               // [0, 72)
    uint32_t kk = kkntl % 6u, ntl = kkntl / 6u;
    uint32_t row = ntl * 16u + (lane & 15u);
    uint32_t col = kk * 32u + (lane >> 4) * 8u + j0;
    float4 v = *(const float4*)(wproj + row * CDIM + col);
    *(uint2*)(wpf + (i - 147456u)) =
        make_uint2((f2u(v.y) << 16) | f2u(v.x), (f2u(v.w) << 16) | f2u(v.z));
  }
}

// ---- bias for transposed S: t = (((w*6+h)*16 + st*4+nt)*64 + lane)*4 + r
//      i (query) = st*16 + (lane&15) ; j (key) = nt*16 + (lane>>4)*4 + r ----
__global__ void __launch_bounds__(256)
biasprep_kernel(const int* __restrict__ rpi, const float* __restrict__ rpb,
                const float* __restrict__ mask, bf16* __restrict__ b5) {
  uint32_t t = blockIdx.x * 256u + threadIdx.x;
  if (t >= 1572864u) return;
  uint32_t w    = t / 24576u;
  uint32_t rem  = t - w * 24576u;
  uint32_t h    = rem / 4096u;
  uint32_t rem2 = rem & 4095u;
  uint32_t stnt = rem2 >> 8, lane = (rem2 >> 2) & 63u, r = rem2 & 3u;
  uint32_t i = (stnt >> 2) * 16u + (lane & 15u);
  uint32_t j = (stnt & 3u) * 16u + (lane >> 4) * 4u + r;
  float v;
  if (j >= NTOK)      v = -1e30f;
  else if (i >= NTOK) v = 0.f;
  else v = rpb[(uint32_t)rpi[i * NTOK + j] * NH + h] + mask[(size_t)w * (NTOK * NTOK) + i * NTOK + j];
  b5[t] = (bf16)v;
}

// ---- fused QKV GEMM: 6 half-W phases, M=64/block, 256 thr (r10 exact) ----
__global__ void __launch_bounds__(256, 4)
qkv_kernel(const float* __restrict__ skip, const float* __restrict__ x,
           const bf16* __restrict__ wbf, const float* __restrict__ bskip,
           const float* __restrict__ bqkv, bf16* __restrict__ qo,
           bf16* __restrict__ kbf, bf16* __restrict__ vbf) {
  extern __shared__ char lds[];
  const uint32_t tid = threadIdx.x, lane = tid & 63u, wv = tid >> 6;  // 4 waves
  const uint32_t l15 = lane & 15u, lg = lane >> 4;
  const uint32_t rowbase = blockIdx.x * 64u;
  const uint32_t arow = rowbase + wv * 16u + l15;

  bf16x8 af[6];
  #pragma unroll
  for (uint32_t p = 0; p < 6u; ++p) {
    if (p == 0u || p == 2u) {
      const float* ap = (p ? x : skip) + (size_t)arow * CDIM + lg * 8u;
      #pragma unroll
      for (uint32_t kk = 0; kk < 6u; ++kk) af[kk] = lda8(ap + kk * 32u);
    }
    if (p) __syncthreads();            // previous copy-out done
    // stage 96 W rows, swizzled
    const bf16* wsrc = wbf + (p < 2u ? WSE_WSKIP + (p & 1u) * 18432u
                                     : (p - 2u) * 18432u);
    for (uint32_t u = tid; u < 2304u; u += 256u) {       // 96 rows x 24 uint4
      uint32_t row = u / 24u, c16 = u - row * 24u;
      uint4 v = *(const uint4*)(wsrc + row * 192u + c16 * 8u);
      *(uint4*)(lds + row * 384u + ((c16 * 16u) ^ ((row & 7u) << 4))) = v;
    }
    __syncthreads();
    f32x4 acc[6] = {};
    #pragma unroll
    for (uint32_t kk = 0; kk < 6u; ++kk)
      #pragma unroll
      for (uint32_t ntl = 0; ntl < 6u; ++ntl) {
        bf16x8 wb = *(const bf16x8*)(lds + swz384(ntl * 16u + l15, kk * 64u + lg * 16u));
        acc[ntl] = __builtin_amdgcn_mfma_f32_16x16x32_bf16(af[kk], wb, acc[ntl], 0, 0, 0);
      }
    __syncthreads();                   // W reads done -> reuse as transpose tile
    const float* bias_base = (p < 2u) ? bskip + (p & 1u) * 96u
                                      : bqkv + (p - 2u) * 96u;
    const float scale = (p < 2u) ? QSCALE : 1.0f;
    #pragma unroll
    for (uint32_t ntl = 0; ntl < 6u; ++ntl) {
      float bias = bias_base[ntl * 16u + l15];
      #pragma unroll
      for (uint32_t r = 0; r < 4u; ++r) {
        uint32_t trow = wv * 16u + lg * 4u + r;
        *(bf16*)(lds + trow * QTSTRIDE + (ntl * 16u + l15) * 2u) =
            (bf16)((acc[ntl][r] + bias) * scale);
      }
    }
    __syncthreads();                   // transpose tile ready
    bf16* dst = (p < 2u) ? qo : ((p < 4u) ? kbf : vbf);
    const uint32_t colofs = (p & 1u) * 96u;
    for (uint32_t i = tid; i < 768u; i += 256u) {        // 64 rows x 12 uint4
      uint32_t row = i / 12u, c16 = i - row * 12u;
      uint4 v = *(const uint4*)(lds + row * QTSTRIDE + c16 * 16u);
      *(uint4*)(dst + (size_t)(rowbase + row) * CDIM + colofs + c16 * 8u) = v;
    }
  }
}

// ---- attention + proj: one block per window, 512 thr (r13 exact) ----
__global__ void __launch_bounds__(512, 6)
attn_kernel(const bf16* __restrict__ qo, const bf16* __restrict__ kbf,
            const bf16* __restrict__ vbf, const bf16* __restrict__ b5L,
            const bf16* __restrict__ wpf, const float* __restrict__ bproj,
            float* __restrict__ out) {
  extern __shared__ char lds[];
  const uint32_t tid = threadIdx.x, lane = tid & 63u, wv = tid >> 6;
  const uint32_t l15 = lane & 15u, lg = lane >> 4;
  const uint32_t grp = wv >> 2, st = wv & 3u;
  const uint32_t win = blockIdx.x;
  char* strip = lds + OFF_STRIP + wv * STRIPB;
  const size_t wrow0 = (size_t)win * NTOK;

  // ---- stage V transposed, tok-pair packed b32 writes ----
  for (uint32_t i = tid; i < 600u; i += 512u) {          // 25 pairs x 24 c16
    uint32_t pair = i / 24u, c16 = i - pair * 24u;
    uint32_t tok0 = pair * 2u;
    const bf16* src = vbf + (wrow0 + tok0) * CDIM + c16 * 8u;
    uint4 a = *(const uint4*)src;
    uint4 b = make_uint4(0u, 0u, 0u, 0u);
    if (tok0 + 1u < NTOK) b = *(const uint4*)(src + CDIM);
    uint32_t base = voff(c16 * 8u) + tok0 * 2u;
    uint32_t aw[4] = {a.x, a.y, a.z, a.w};
    uint32_t bw[4] = {b.x, b.y, b.z, b.w};
    #pragma unroll
    for (uint32_t q = 0; q < 4u; ++q) {
      *(uint32_t*)(lds + base + (2u * q) * 144u)      = (aw[q] & 0xffffu) | (bw[q] << 16);
      *(uint32_t*)(lds + base + (2u * q + 1u) * 144u) = (aw[q] >> 16) | (bw[q] & 0xffff0000u);
    }
  }
  for (uint32_t i = tid; i < 1344u; i += 512u) {         // zero toks 50..63
    uint32_t ch = i / 7u, p = i - ch * 7u;
    *(uint32_t*)(lds + voff(ch) + (50u + p * 2u) * 2u) = 0u;
  }
  __syncthreads();

  f32x4 oacc[3][2];
  uint32_t qrow = st * 16u + l15; if (qrow > 48u) qrow = 48u;
  const uint32_t w6 = win & 63u;

  #pragma unroll
  for (uint32_t hl = 0; hl < 3u; ++hl) {
    uint32_t h = grp * 3u + hl;
    bf16x8 qb = *(const bf16x8*)(qo + (wrow0 + qrow) * CDIM + h * 32u + lg * 8u);
    f32x4 s[4];
    #pragma unroll
    for (uint32_t nt = 0; nt < 4u; ++nt) {
      uint32_t krow = nt * 16u + l15; if (krow > 48u) krow = 48u;
      bf16x8 ka = *(const bf16x8*)(kbf + (wrow0 + krow) * CDIM + h * 32u + lg * 8u);
      f32x4 z = {};
      s[nt] = __builtin_amdgcn_mfma_f32_16x16x32_bf16(ka, qb, z, 0, 0, 0);
    }
    const bf16* bp = b5L + ((((w6 * 6u + h) * 16u) + st * 4u) << 8) + lane * 4u;
    #pragma unroll
    for (uint32_t nt = 0; nt < 4u; ++nt) {
      uint2 bv = *(const uint2*)(bp + nt * 256u);
      s[nt][0] += bfu2f(bv.x);
      s[nt][1] += bfh2f(bv.x);
      s[nt][2] += bfu2f(bv.y);
      s[nt][3] += bfh2f(bv.y);
    }
    float mm = s[0][0];
    #pragma unroll
    for (uint32_t nt = 0; nt < 4u; ++nt)
      #pragma unroll
      for (uint32_t r = 0; r < 4u; ++r) mm = fmaxf(mm, s[nt][r]);
    mm = fmaxf(mm, __shfl_xor(mm, 16)); mm = fmaxf(mm, __shfl_xor(mm, 32));
    float ss = 0.f;
    #pragma unroll
    for (uint32_t nt = 0; nt < 4u; ++nt)
      #pragma unroll
      for (uint32_t r = 0; r < 4u; ++r) { float p = __expf(s[nt][r] - mm); s[nt][r] = p; ss += p; }
    ss += __shfl_xor(ss, 16); ss += __shfl_xor(ss, 32);
    float inv = 1.f / ss;
    #pragma unroll
    for (uint32_t nt = 0; nt < 4u; ++nt) {
      uint2 w;
      w.x = (f2u(s[nt][1] * inv) << 16) | f2u(s[nt][0] * inv);
      w.y = (f2u(s[nt][3] * inv) << 16) | f2u(s[nt][2] * inv);
      *(uint2*)(strip + l15 * 144u + nt * 32u + lg * 8u) = w;
    }
    bf16x8 pb0 = *(const bf16x8*)(strip + l15 * 144u + lg * 16u);
    bf16x8 pb1 = *(const bf16x8*)(strip + l15 * 144u + 64u + lg * 16u);
    #pragma unroll
    for (uint32_t nt2 = 0; nt2 < 2u; ++nt2) {
      uint32_t ch = h * 32u + nt2 * 16u + l15;
      uint32_t va = voff(ch);
      bf16x8 va0 = *(const bf16x8*)(lds + va + lg * 16u);
      bf16x8 va1 = *(const bf16x8*)(lds + va + 64u + lg * 16u);
      f32x4 z = {};
      f32x4 o = __builtin_amdgcn_mfma_f32_16x16x32_bf16(va0, pb0, z, 0, 0, 0);
      oacc[hl][nt2] = __builtin_amdgcn_mfma_f32_16x16x32_bf16(va1, pb1, o, 0, 0, 0);
    }
  }

  __syncthreads();   // all VT/strip reads done -> reuse VT region as O tile

  {
    uint32_t orow = (st * 16u + l15) * OSTRIDE;
    #pragma unroll
    for (uint32_t hl = 0; hl < 3u; ++hl)
      #pragma unroll
      for (uint32_t nt2 = 0; nt2 < 2u; ++nt2) {
        uint32_t d0 = (grp * 3u + hl) * 32u + nt2 * 16u + lg * 4u;
        uint2 w;
        w.x = (f2u(oacc[hl][nt2][1]) << 16) | f2u(oacc[hl][nt2][0]);
        w.y = (f2u(oacc[hl][nt2][3]) << 16) | f2u(oacc[hl][nt2][2]);
        *(uint2*)(lds + orow + d0 * 2u) = w;
      }
  }

  __syncthreads();   // O tile ready -> fused proj (fragment-ordered W, coalesced)

  {
    const uint32_t st2 = (wv & 3u) * 16u;        // row strip
    const uint32_t ntlg0 = (wv >> 2) * 6u;       // output-channel half
    bf16x8 paf[6];
    #pragma unroll
    for (uint32_t kk = 0; kk < 6u; ++kk)
      paf[kk] = *(const bf16x8*)(lds + (st2 + l15) * OSTRIDE + kk * 64u + lg * 16u);
    f32x4 pacc[6] = {};
    #pragma unroll
    for (uint32_t kk = 0; kk < 6u; ++kk)
      #pragma unroll
      for (uint32_t ntl = 0; ntl < 6u; ++ntl) {
        bf16x8 wb = *(const bf16x8*)(wpf + (((ntlg0 + ntl) * 6u + kk) * 64u + lane) * 8u);
        pacc[ntl] = __builtin_amdgcn_mfma_f32_16x16x32_bf16(paf[kk], wb, pacc[ntl], 0, 0, 0);
      }
    #pragma unroll
    for (uint32_t ntl = 0; ntl < 6u; ++ntl) {
      uint32_t ch = (ntlg0 + ntl) * 16u + l15;
      float bias = bproj[ch];
      #pragma unroll
      for (uint32_t r = 0; r < 4u; ++r) {
        uint32_t row = st2 + lg * 4u + r;
        if (row < NTOK)
          out[(wrow0 + row) * CDIM + ch] = pacc[ntl][r] + bias;
      }
    }
  }
}

extern "C" void kernel_launch(void* const* d_in, const int* in_sizes, int n_in,
                              void* d_out, int out_size, void* d_ws, size_t ws_size,
                              hipStream_t stream) {
  const float* x     = (const float*)d_in[0];
  const float* skip  = (const float*)d_in[1];
  const float* mask  = (const float*)d_in[2];
  const int*   rpi   = (const int*)  d_in[3];
  const float* rpb   = (const float*)d_in[4];
  const float* wqkv  = (const float*)d_in[5];
  const float* bqkv  = (const float*)d_in[6];
  const float* wskip = (const float*)d_in[7];
  const float* bskip = (const float*)d_in[8];
  const float* wproj = (const float*)d_in[9];
  const float* bproj = (const float*)d_in[10];

  char* ws = (char*)d_ws;
  bf16* wbf  = (bf16*)(ws + WSB_W);
  bf16* wpf  = (bf16*)(ws + WSB_WPF);
  bf16* b5L  = (bf16*)(ws + WSB_B5);
  bf16* qo   = (bf16*)(ws + WSB_QO);
  bf16* kbf  = (bf16*)(ws + WSB_K);
  bf16* vbf  = (bf16*)(ws + WSB_V);

  uint32_t nwin  = (uint32_t)(in_sizes[0] / (NTOK * CDIM));
  uint32_t nrows = nwin * NTOK;            // 200704, divisible by 64
  uint32_t ngb   = nrows / 64u;

  hipFuncSetAttribute((const void*)qkv_kernel,  hipFuncAttributeMaxDynamicSharedMemorySize, (int)QKV_LDS);
  hipFuncSetAttribute((const void*)attn_kernel, hipFuncAttributeMaxDynamicSharedMemorySize, (int)ATTN_LDS);

  wcvt_kernel<<<180, 256, 0, stream>>>(wqkv, wskip, wproj, wbf, wpf);
  biasprep_kernel<<<6144, 256, 0, stream>>>(rpi, rpb, mask, b5L);
  qkv_kernel<<<ngb, 256, QKV_LDS, stream>>>(skip, x, wbf, bskip, bqkv, qo, kbf, vbf);
  attn_kernel<<<nwin, 512, ATTN_LDS, stream>>>(qo, kbf, vbf, b5L, wpf, bproj, (float*)d_out);
}

// Round 15
// 309.997 us; speedup vs baseline: 2.5946x; 1.0616x over previous
//
#include <hip/hip_runtime.h>
#include <hip/hip_bf16.h>
#include <stdint.h>

// WindowMSA, round 15: qkv rebuilt lean; attn unchanged (r13/r14 exact).
//  qkv changes vs r14:
//   - W staging via __builtin_amdgcn_global_load_lds width=16 (async DMA,
//     no VGPR round trip). LDS dest linear; XOR-swizzle moved to the GLOBAL
//     source (c16 ^ (row&7), involution) per both-sides-or-neither rule.
//   - MFMA operands swapped: acc = mfma(W,x) -> lane holds 4 consecutive
//     output channels -> transpose tile written with 6 packed b64 ds_writes
//     (was 24 scalar u16).
//   - Copy-out is wave-local (own 16 rows): same-wave DS ordering, one
//     barrier removed (3/phase).
//   - M=128, 512 thr: 4 blocks x 512 = 2048 thr/CU (100% static occupancy),
//     half the blocks -> half the W L2 traffic.

typedef __bf16 bf16;
typedef __attribute__((ext_vector_type(8))) __bf16 bf16x8;
typedef __attribute__((ext_vector_type(4))) float f32x4;

#define CDIM 192
#define NH 6
#define NTOK 49
#define QSCALE 0.17677669529663687f

// ws byte offsets
#define WSB_W      0u          // linear bf16 weights: wqkv|wskip|wproj = 294912 B
#define WSE_WSKIP  73728u      // elem offsets within linear blob
#define WSB_WPF    294912u     // wproj fragment-ordered: 36864 bf16 = 73728 B
#define WSB_B5     368640u     // b5L: 64*6*16*256 bf16 = 3,145,728 B
#define WSB_QO     3514368u    // 200704*192 bf16 = 77,070,336 B
#define WSB_K      80584704u
#define WSB_V      157655040u  // end 234,725,376

// qkv LDS: 96-row W stage (36864 B); transpose tile reuses first 26624 B
#define QKV_LDS  36864u
#define QTSTRIDE 208u

// attn LDS: VT region 27904 (voff(191)+128 = 27808), 8 strips of 2304
#define OFF_STRIP 27904u
#define STRIPB    2304u
#define ATTN_LDS  46336u
#define OSTRIDE   400u         // O tile row stride (reuses VT region)

__device__ __forceinline__ uint32_t swz384(uint32_t row, uint32_t b) {
  return row * 384u + (b ^ ((row & 7u) << 4));
}
__device__ __forceinline__ uint32_t voff(uint32_t ch) {   // VT row base, 16B-aligned, monotone
  return ch * 144u + ((ch >> 4) << 4);
}
__device__ __forceinline__ uint32_t f2u(float f) { bf16 h = (bf16)f; return (uint32_t)__builtin_bit_cast(uint16_t, h); }
__device__ __forceinline__ bf16x8 lda8(const float* p) {
  float4 w0 = *(const float4*)p;
  float4 w1 = *(const float4*)(p + 4);
  bf16x8 b = {(bf16)w0.x, (bf16)w0.y, (bf16)w0.z, (bf16)w0.w,
              (bf16)w1.x, (bf16)w1.y, (bf16)w1.z, (bf16)w1.w};
  return b;
}
__device__ __forceinline__ float bfu2f(uint32_t lo16) { return __builtin_bit_cast(float, lo16 << 16); }
__device__ __forceinline__ float bfh2f(uint32_t hi16) { return __builtin_bit_cast(float, hi16 & 0xffff0000u); }

__device__ __forceinline__ void gload16(const void* g, void* l) {
  __builtin_amdgcn_global_load_lds(
      (const __attribute__((address_space(1))) uint32_t*)g,
      (__attribute__((address_space(3))) uint32_t*)l, 16, 0, 0);
}

// ---- weights f32 -> bf16 (linear) + wproj fragment-ordered copy ----
__global__ void __launch_bounds__(256)
wcvt_kernel(const float* __restrict__ wqkv, const float* __restrict__ wskip,
            const float* __restrict__ wproj, bf16* __restrict__ ws,
            bf16* __restrict__ wpf) {
  uint32_t i4 = blockIdx.x * 256u + threadIdx.x;
  uint32_t i = i4 * 4u;
  if (i < 147456u) {
    float4 v;
    if (i < 73728u)       v = *(const float4*)(wqkv + i);
    else if (i < 110592u) v = *(const float4*)(wskip + (i - 73728u));
    else                  v = *(const float4*)(wproj + (i - 110592u));
    *(uint2*)(ws + i) = make_uint2((f2u(v.y) << 16) | f2u(v.x), (f2u(v.w) << 16) | f2u(v.z));
  } else if (i < 184320u) {
    // wpf[((ntl*6+kk)*64+lane)*8+j] = wproj[ntl*16+(lane&15)][kk*32+(lane>>4)*8+j]
    uint32_t f4 = i4 - 36864u;              // [0, 9216)
    uint32_t j0 = (f4 & 1u) * 4u;
    uint32_t lane = (f4 >> 1) & 63u;
    uint32_t kkntl = f4 >> 7;               // [0, 72)
    uint32_t kk = kkntl % 6u, ntl = kkntl / 6u;
    uint32_t row = ntl * 16u + (lane & 15u);
    uint32_t col = kk * 32u + (lane >> 4) * 8u + j0;
    float4 v = *(const float4*)(wproj + row * CDIM + col);
    *(uint2*)(wpf + (i - 147456u)) =
        make_uint2((f2u(v.y) << 16) | f2u(v.x), (f2u(v.w) << 16) | f2u(v.z));
  }
}

// ---- bias for transposed S: t = (((w*6+h)*16 + st*4+nt)*64 + lane)*4 + r
//      i (query) = st*16 + (lane&15) ; j (key) = nt*16 + (lane>>4)*4 + r ----
__global__ void __launch_bounds__(256)
biasprep_kernel(const int* __restrict__ rpi, const float* __restrict__ rpb,
                const float* __restrict__ mask, bf16* __restrict__ b5) {
  uint32_t t = blockIdx.x * 256u + threadIdx.x;
  if (t >= 1572864u) return;
  uint32_t w    = t / 24576u;
  uint32_t rem  = t - w * 24576u;
  uint32_t h    = rem / 4096u;
  uint32_t rem2 = rem & 4095u;
  uint32_t stnt = rem2 >> 8, lane = (rem2 >> 2) & 63u, r = rem2 & 3u;
  uint32_t i = (stnt >> 2) * 16u + (lane & 15u);
  uint32_t j = (stnt & 3u) * 16u + (lane >> 4) * 4u + r;
  float v;
  if (j >= NTOK)      v = -1e30f;
  else if (i >= NTOK) v = 0.f;
  else v = rpb[(uint32_t)rpi[i * NTOK + j] * NH + h] + mask[(size_t)w * (NTOK * NTOK) + i * NTOK + j];
  b5[t] = (bf16)v;
}

// ---- fused QKV GEMM: 6 half-W phases, M=128/block, 512 thr ----
__global__ void __launch_bounds__(512, 4)
qkv_kernel(const float* __restrict__ skip, const float* __restrict__ x,
           const bf16* __restrict__ wbf, const float* __restrict__ bskip,
           const float* __restrict__ bqkv, bf16* __restrict__ qo,
           bf16* __restrict__ kbf, bf16* __restrict__ vbf) {
  extern __shared__ char lds[];
  const uint32_t tid = threadIdx.x, lane = tid & 63u, wv = tid >> 6;  // 8 waves
  const uint32_t l15 = lane & 15u, lg = lane >> 4;
  const uint32_t rowbase = blockIdx.x * 128u;
  const uint32_t arow = rowbase + wv * 16u + l15;

  bf16x8 af[6];
  #pragma unroll
  for (uint32_t p = 0; p < 6u; ++p) {
    if (p == 0u || p == 2u) {
      const float* ap = (p ? x : skip) + (size_t)arow * CDIM + lg * 8u;
      #pragma unroll
      for (uint32_t kk = 0; kk < 6u; ++kk) af[kk] = lda8(ap + kk * 32u);
    }
    if (p) __syncthreads();            // prior copy-out LDS reads done
    // ---- stage 96 W rows via global_load_lds (linear LDS, pre-swizzled src) ----
    const bf16* wsrc = wbf + (p < 2u ? WSE_WSKIP + (p & 1u) * 18432u
                                     : (p - 2u) * 18432u);
    for (uint32_t u0 = wv * 64u; u0 < 2304u; u0 += 512u) {   // wave-uniform base
      uint32_t u = u0 + lane;
      uint32_t row = u / 24u, c16 = u - row * 24u;
      gload16(wsrc + row * 192u + ((c16 ^ (row & 7u)) << 3), lds + u0 * 16u);
    }
    __syncthreads();                   // vmcnt drain: W resident in LDS
    // ---- MFMA, swapped: D[ch][m] = W x^T ; lane: m=l15, ch=ntl*16+lg*4+r ----
    f32x4 acc[6] = {};
    #pragma unroll
    for (uint32_t kk = 0; kk < 6u; ++kk)
      #pragma unroll
      for (uint32_t ntl = 0; ntl < 6u; ++ntl) {
        bf16x8 wb = *(const bf16x8*)(lds + swz384(ntl * 16u + l15, kk * 64u + lg * 16u));
        acc[ntl] = __builtin_amdgcn_mfma_f32_16x16x32_bf16(wb, af[kk], acc[ntl], 0, 0, 0);
      }
    __syncthreads();                   // all W reads done -> reuse as tile
    const float* bias_base = (p < 2u) ? bskip + (p & 1u) * 96u
                                      : bqkv + (p - 2u) * 96u;
    const float scale = (p < 2u) ? QSCALE : 1.0f;
    // packed b64 tile writes: row m = wv*16+l15, 4 consecutive channels
    #pragma unroll
    for (uint32_t ntl = 0; ntl < 6u; ++ntl) {
      float4 bv = *(const float4*)(bias_base + ntl * 16u + lg * 4u);
      uint2 w;
      w.x = (f2u((acc[ntl][1] + bv.y) * scale) << 16) | f2u((acc[ntl][0] + bv.x) * scale);
      w.y = (f2u((acc[ntl][3] + bv.w) * scale) << 16) | f2u((acc[ntl][2] + bv.z) * scale);
      *(uint2*)(lds + (wv * 16u + l15) * QTSTRIDE + (ntl * 16u + lg * 4u) * 2u) = w;
    }
    // wave-local copy-out (own 16 rows x 192B): same-wave DS, no barrier
    bf16* dst = (p < 2u) ? qo : ((p < 4u) ? kbf : vbf);
    const uint32_t colofs = (p & 1u) * 96u;
    #pragma unroll
    for (uint32_t it = 0; it < 3u; ++it) {
      uint32_t u = it * 64u + lane;
      uint32_t r16 = u / 12u, c16 = u - r16 * 12u;
      uint4 v = *(const uint4*)(lds + (wv * 16u + r16) * QTSTRIDE + c16 * 16u);
      *(uint4*)(dst + (size_t)(rowbase + wv * 16u + r16) * CDIM + colofs + c16 * 8u) = v;
    }
  }
}

// ---- attention + proj: one block per window, 512 thr (r13 exact) ----
__global__ void __launch_bounds__(512, 6)
attn_kernel(const bf16* __restrict__ qo, const bf16* __restrict__ kbf,
            const bf16* __restrict__ vbf, const bf16* __restrict__ b5L,
            const bf16* __restrict__ wpf, const float* __restrict__ bproj,
            float* __restrict__ out) {
  extern __shared__ char lds[];
  const uint32_t tid = threadIdx.x, lane = tid & 63u, wv = tid >> 6;
  const uint32_t l15 = lane & 15u, lg = lane >> 4;
  const uint32_t grp = wv >> 2, st = wv & 3u;
  const uint32_t win = blockIdx.x;
  char* strip = lds + OFF_STRIP + wv * STRIPB;
  const size_t wrow0 = (size_t)win * NTOK;

  // ---- stage V transposed, tok-pair packed b32 writes ----
  for (uint32_t i = tid; i < 600u; i += 512u) {          // 25 pairs x 24 c16
    uint32_t pair = i / 24u, c16 = i - pair * 24u;
    uint32_t tok0 = pair * 2u;
    const bf16* src = vbf + (wrow0 + tok0) * CDIM + c16 * 8u;
    uint4 a = *(const uint4*)src;
    uint4 b = make_uint4(0u, 0u, 0u, 0u);
    if (tok0 + 1u < NTOK) b = *(const uint4*)(src + CDIM);
    uint32_t base = voff(c16 * 8u) + tok0 * 2u;
    uint32_t aw[4] = {a.x, a.y, a.z, a.w};
    uint32_t bw[4] = {b.x, b.y, b.z, b.w};
    #pragma unroll
    for (uint32_t q = 0; q < 4u; ++q) {
      *(uint32_t*)(lds + base + (2u * q) * 144u)      = (aw[q] & 0xffffu) | (bw[q] << 16);
      *(uint32_t*)(lds + base + (2u * q + 1u) * 144u) = (aw[q] >> 16) | (bw[q] & 0xffff0000u);
    }
  }
  for (uint32_t i = tid; i < 1344u; i += 512u) {         // zero toks 50..63
    uint32_t ch = i / 7u, p = i - ch * 7u;
    *(uint32_t*)(lds + voff(ch) + (50u + p * 2u) * 2u) = 0u;
  }
  __syncthreads();

  f32x4 oacc[3][2];
  uint32_t qrow = st * 16u + l15; if (qrow > 48u) qrow = 48u;
  const uint32_t w6 = win & 63u;

  #pragma unroll
  for (uint32_t hl = 0; hl < 3u; ++hl) {
    uint32_t h = grp * 3u + hl;
    bf16x8 qb = *(const bf16x8*)(qo + (wrow0 + qrow) * CDIM + h * 32u + lg * 8u);
    f32x4 s[4];
    #pragma unroll
    for (uint32_t nt = 0; nt < 4u; ++nt) {
      uint32_t krow = nt * 16u + l15; if (krow > 48u) krow = 48u;
      bf16x8 ka = *(const bf16x8*)(kbf + (wrow0 + krow) * CDIM + h * 32u + lg * 8u);
      f32x4 z = {};
      s[nt] = __builtin_amdgcn_mfma_f32_16x16x32_bf16(ka, qb, z, 0, 0, 0);
    }
    const bf16* bp = b5L + ((((w6 * 6u + h) * 16u) + st * 4u) << 8) + lane * 4u;
    #pragma unroll
    for (uint32_t nt = 0; nt < 4u; ++nt) {
      uint2 bv = *(const uint2*)(bp + nt * 256u);
      s[nt][0] += bfu2f(bv.x);
      s[nt][1] += bfh2f(bv.x);
      s[nt][2] += bfu2f(bv.y);
      s[nt][3] += bfh2f(bv.y);
    }
    float mm = s[0][0];
    #pragma unroll
    for (uint32_t nt = 0; nt < 4u; ++nt)
      #pragma unroll
      for (uint32_t r = 0; r < 4u; ++r) mm = fmaxf(mm, s[nt][r]);
    mm = fmaxf(mm, __shfl_xor(mm, 16)); mm = fmaxf(mm, __shfl_xor(mm, 32));
    float ss = 0.f;
    #pragma unroll
    for (uint32_t nt = 0; nt < 4u; ++nt)
      #pragma unroll
      for (uint32_t r = 0; r < 4u; ++r) { float p = __expf(s[nt][r] - mm); s[nt][r] = p; ss += p; }
    ss += __shfl_xor(ss, 16); ss += __shfl_xor(ss, 32);
    float inv = 1.f / ss;
    #pragma unroll
    for (uint32_t nt = 0; nt < 4u; ++nt) {
      uint2 w;
      w.x = (f2u(s[nt][1] * inv) << 16) | f2u(s[nt][0] * inv);
      w.y = (f2u(s[nt][3] * inv) << 16) | f2u(s[nt][2] * inv);
      *(uint2*)(strip + l15 * 144u + nt * 32u + lg * 8u) = w;
    }
    bf16x8 pb0 = *(const bf16x8*)(strip + l15 * 144u + lg * 16u);
    bf16x8 pb1 = *(const bf16x8*)(strip + l15 * 144u + 64u + lg * 16u);
    #pragma unroll
    for (uint32_t nt2 = 0; nt2 < 2u; ++nt2) {
      uint32_t ch = h * 32u + nt2 * 16u + l15;
      uint32_t va = voff(ch);
      bf16x8 va0 = *(const bf16x8*)(lds + va + lg * 16u);
      bf16x8 va1 = *(const bf16x8*)(lds + va + 64u + lg * 16u);
      f32x4 z = {};
      f32x4 o = __builtin_amdgcn_mfma_f32_16x16x32_bf16(va0, pb0, z, 0, 0, 0);
      oacc[hl][nt2] = __builtin_amdgcn_mfma_f32_16x16x32_bf16(va1, pb1, o, 0, 0, 0);
    }
  }

  __syncthreads();   // all VT/strip reads done -> reuse VT region as O tile

  {
    uint32_t orow = (st * 16u + l15) * OSTRIDE;
    #pragma unroll
    for (uint32_t hl = 0; hl < 3u; ++hl)
      #pragma unroll
      for (uint32_t nt2 = 0; nt2 < 2u; ++nt2) {
        uint32_t d0 = (grp * 3u + hl) * 32u + nt2 * 16u + lg * 4u;
        uint2 w;
        w.x = (f2u(oacc[hl][nt2][1]) << 16) | f2u(oacc[hl][nt2][0]);
        w.y = (f2u(oacc[hl][nt2][3]) << 16) | f2u(oacc[hl][nt2][2]);
        *(uint2*)(lds + orow + d0 * 2u) = w;
      }
  }

  __syncthreads();   // O tile ready -> fused proj (fragment-ordered W, coalesced)

  {
    const uint32_t st2 = (wv & 3u) * 16u;        // row strip
    const uint32_t ntlg0 = (wv >> 2) * 6u;       // output-channel half
    bf16x8 paf[6];
    #pragma unroll
    for (uint32_t kk = 0; kk < 6u; ++kk)
      paf[kk] = *(const bf16x8*)(lds + (st2 + l15) * OSTRIDE + kk * 64u + lg * 16u);
    f32x4 pacc[6] = {};
    #pragma unroll
    for (uint32_t kk = 0; kk < 6u; ++kk)
      #pragma unroll
      for (uint32_t ntl = 0; ntl < 6u; ++ntl) {
        bf16x8 wb = *(const bf16x8*)(wpf + (((ntlg0 + ntl) * 6u + kk) * 64u + lane) * 8u);
        pacc[ntl] = __builtin_amdgcn_mfma_f32_16x16x32_bf16(paf[kk], wb, pacc[ntl], 0, 0, 0);
      }
    #pragma unroll
    for (uint32_t ntl = 0; ntl < 6u; ++ntl) {
      uint32_t ch = (ntlg0 + ntl) * 16u + l15;
      float bias = bproj[ch];
      #pragma unroll
      for (uint32_t r = 0; r < 4u; ++r) {
        uint32_t row = st2 + lg * 4u + r;
        if (row < NTOK)
          out[(wrow0 + row) * CDIM + ch] = pacc[ntl][r] + bias;
      }
    }
  }
}

extern "C" void kernel_launch(void* const* d_in, const int* in_sizes, int n_in,
                              void* d_out, int out_size, void* d_ws, size_t ws_size,
                              hipStream_t stream) {
  const float* x     = (const float*)d_in[0];
  const float* skip  = (const float*)d_in[1];
  const float* mask  = (const float*)d_in[2];
  const int*   rpi   = (const int*)  d_in[3];
  const float* rpb   = (const float*)d_in[4];
  const float* wqkv  = (const float*)d_in[5];
  const float* bqkv  = (const float*)d_in[6];
  const float* wskip = (const float*)d_in[7];
  const float* bskip = (const float*)d_in[8];
  const float* wproj = (const float*)d_in[9];
  const float* bproj = (const float*)d_in[10];

  char* ws = (char*)d_ws;
  bf16* wbf  = (bf16*)(ws + WSB_W);
  bf16* wpf  = (bf16*)(ws + WSB_WPF);
  bf16* b5L  = (bf16*)(ws + WSB_B5);
  bf16* qo   = (bf16*)(ws + WSB_QO);
  bf16* kbf  = (bf16*)(ws + WSB_K);
  bf16* vbf  = (bf16*)(ws + WSB_V);

  uint32_t nwin  = (uint32_t)(in_sizes[0] / (NTOK * CDIM));
  uint32_t nrows = nwin * NTOK;            // 200704, divisible by 128
  uint32_t ngb   = nrows / 128u;

  hipFuncSetAttribute((const void*)qkv_kernel,  hipFuncAttributeMaxDynamicSharedMemorySize, (int)QKV_LDS);
  hipFuncSetAttribute((const void*)attn_kernel, hipFuncAttributeMaxDynamicSharedMemorySize, (int)ATTN_LDS);

  wcvt_kernel<<<180, 256, 0, stream>>>(wqkv, wskip, wproj, wbf, wpf);
  biasprep_kernel<<<6144, 256, 0, stream>>>(rpi, rpb, mask, b5L);
  qkv_kernel<<<ngb, 512, QKV_LDS, stream>>>(skip, x, wbf, bskip, bqkv, qo, kbf, vbf);
  attn_kernel<<<nwin, 512, ATTN_LDS, stream>>>(qo, kbf, vbf, b5L, wpf, bproj, (float*)d_out);
}